// Round 11
// baseline (207.929 us; speedup 1.0000x reference)
//
#include <hip/hip_runtime.h>
#include <hip/hip_bf16.h>
#include <cstdint>
#include <math.h>

// Problem constants
#define SEQ    2048
#define DMODEL 1024
#define NHEAD  16
#define DHEAD  64
#define NZPAD  32   // per-row nonzero count padded to 32 (analytic max = 26)

// MEASUREMENT ROUND: rep-counts chosen to push every dispatch past the ~41us
// fill threshold so rocprof top-5 finally shows per-kernel durations+counters.
// All bodies are idempotent (pure functions of inputs) -> correctness intact.
// True per-kernel time = dispatch_dur / REP.
#define REP_PREP  4
#define REP_PROJ  2
#define REP_ATTN  4
#define REP_FINAL 4

typedef __bf16 bf16;
typedef __bf16 bf16x4 __attribute__((ext_vector_type(4)));
typedef __bf16 bf16x8 __attribute__((ext_vector_type(8)));
typedef float  f32x4  __attribute__((ext_vector_type(4)));

typedef __attribute__((address_space(3))) uint32_t lds_u32;
typedef __attribute__((address_space(1))) const uint32_t global_u32;

__device__ __forceinline__ void async_load16(const void* g, void* l) {
    __builtin_amdgcn_global_load_lds((global_u32*)g, (lds_u32*)l, 16, 0, 0);
}

// Analytic sparse-layout support for ORIGIN_SHAPE=(8,16,16), LOCAL_BLOCKS=3.
__device__ __forceinline__ int support_idx(int s, int c, int tt, int hh,
                                           int cnt) {
    const int jA = c * 256 + (s & 255);                    // axial-T, c < tt
    const int jB = (s & 0x700) + (c - tt) * 16 + (s & 15); // axial-H
    const int jC = s - (cnt - 1 - c);                      // causal window
    return c < tt ? jA : (c < tt + hh ? jB : (c < cnt ? jC : s));
}

// ---------------------------------------------------------------------------
#define CAST_BLOCKS 1536
#define TR_BLOCKS   1024

__global__ __launch_bounds__(256) void prep_kernel(
    const float* __restrict__ q, const float* __restrict__ k, const float* __restrict__ v,
    bf16* __restrict__ qx, bf16* __restrict__ kx, bf16* __restrict__ vx,
    const float* __restrict__ w0, const float* __restrict__ w1,
    const float* __restrict__ w2, const float* __restrict__ w3,
    bf16* __restrict__ t0, bf16* __restrict__ t1,
    bf16* __restrict__ t2, bf16* __restrict__ t3) {
    __shared__ float tile[64][65];
    const int bid = blockIdx.x;
    for (int rep = 0; rep < REP_PREP; ++rep) {
        if (bid < CAST_BLOCKS) {
            const int z = bid >> 9;               // 512 blocks per tensor
            const float* src = (z == 0) ? q : (z == 1) ? k : v;
            bf16* dst        = (z == 0) ? qx : (z == 1) ? kx : vx;
            const int i = (bid & 511) * 256 + threadIdx.x;
            const float4* s4 = (const float4*)src;
            float4 a0 = s4[i * 4 + 0];
            float4 a1 = s4[i * 4 + 1];
            float4 a2 = s4[i * 4 + 2];
            float4 a3 = s4[i * 4 + 3];
            bf16x8 o0, o1;
            o0[0] = (bf16)a0.x; o0[1] = (bf16)a0.y; o0[2] = (bf16)a0.z; o0[3] = (bf16)a0.w;
            o0[4] = (bf16)a1.x; o0[5] = (bf16)a1.y; o0[6] = (bf16)a1.z; o0[7] = (bf16)a1.w;
            o1[0] = (bf16)a2.x; o1[1] = (bf16)a2.y; o1[2] = (bf16)a2.z; o1[3] = (bf16)a2.w;
            o1[4] = (bf16)a3.x; o1[5] = (bf16)a3.y; o1[6] = (bf16)a3.z; o1[7] = (bf16)a3.w;
            ((bf16x8*)dst)[i * 2 + 0] = o0;
            ((bf16x8*)dst)[i * 2 + 1] = o1;
        } else {
            const int b = bid - CAST_BLOCKS;
            const int z = b >> 8, rem = b & 255;
            const float* w = (z == 0) ? w0 : (z == 1) ? w1 : (z == 2) ? w2 : w3;
            bf16* t        = (z == 0) ? t0 : (z == 1) ? t1 : (z == 2) ? t2 : t3;
            const int kb = (rem >> 4) * 64, nb = (rem & 15) * 64;
            const int c4 = threadIdx.x & 15, rg = threadIdx.x >> 4;
#pragma unroll
            for (int i = 0; i < 4; ++i) {
                const int row = rg * 4 + i;
                const float4 vv = *(const float4*)&w[(size_t)(kb + row) * DMODEL + nb + c4 * 4];
                tile[row][c4 * 4 + 0] = vv.x; tile[row][c4 * 4 + 1] = vv.y;
                tile[row][c4 * 4 + 2] = vv.z; tile[row][c4 * 4 + 3] = vv.w;
            }
            __syncthreads();
#pragma unroll
            for (int i = 0; i < 4; ++i) {
                const int n = rg * 4 + i;
                bf16x4 o;
                o[0] = (bf16)tile[c4 * 4 + 0][n]; o[1] = (bf16)tile[c4 * 4 + 1][n];
                o[2] = (bf16)tile[c4 * 4 + 2][n]; o[3] = (bf16)tile[c4 * 4 + 3][n];
                *(bf16x4*)&t[(size_t)(nb + n) * DMODEL + kb + c4 * 4] = o;
            }
            __syncthreads();   // rep boundary: tile[] reused
        }
    }
}

// ---------------------------------------------------------------------------
// proj3: TM=64, BK=64, 2-deep counted vmcnt(6) pipeline, XOR-swizzled LDS,
// XCD-chunked 1-D grid (round-5 best-measured structure).
__global__ __launch_bounds__(256) void proj3_kernel(
    const bf16* __restrict__ qx, const bf16* __restrict__ kx, const bf16* __restrict__ vx,
    const bf16* __restrict__ wqT, const bf16* __restrict__ wkT, const bf16* __restrict__ wvT,
    const float* __restrict__ bq, const float* __restrict__ bk, const float* __restrict__ bv,
    bf16* __restrict__ qp, bf16* __restrict__ kp, bf16* __restrict__ vp) {
    constexpr int K = 1024, N = 1024, BK = 64, TM = 64, MI = 2;
    constexpr int ACH = TM * (BK / 8);        // 512 chunks
    constexpr int TCH = ACH + 128 * (BK / 8); // 1536 chunks -> 6 per thread

    const int orig = blockIdx.x;
    const int flat = (orig & 7) * 96 + (orig >> 3);
    const int z = flat >> 8;
    const int rem = flat & 255;
    const int m0 = (rem >> 3) * TM, n0 = (rem & 7) * 128;

    const bf16* A   = (z == 0) ? qx : (z == 1) ? kx : vx;
    const bf16* BT  = (z == 0) ? wqT : (z == 1) ? wkT : wvT;
    const float* bi = (z == 0) ? bq : (z == 1) ? bk : bv;
    bf16* C         = (z == 0) ? qp : (z == 1) ? kp : vp;

    __shared__ bf16 sA[2][TM * BK];
    __shared__ bf16 sB[2][128 * BK];
    const int tid = threadIdx.x;
    const int w = tid >> 6, lane = tid & 63;
    const int wm = w >> 1, wn = w & 1;
    const int lr = lane & 15, quad = lane >> 4;

    float bia[4];
#pragma unroll
    for (int ni = 0; ni < 4; ++ni) bia[ni] = bi[n0 + wn * 64 + ni * 16 + lr];

    auto stage = [&](int buf, int kt) {
#pragma unroll
        for (int kk = 0; kk < TCH / 256; ++kk) {
            const int cb = kk * 256 + w * 64;
            const int p  = cb + lane;
            if (cb < ACH) {
                const int row = p >> 3, chl = p & 7;
                const int chg = chl ^ (row & 7);
                async_load16(A + (size_t)(m0 + row) * K + kt + chg * 8,
                             (char*)&sA[buf][0] + cb * 16);
            } else {
                const int p2 = p - ACH, row = p2 >> 3, chl = p2 & 7;
                const int chg = chl ^ (row & 7);
                async_load16(BT + (size_t)(n0 + row) * K + kt + chg * 8,
                             (char*)&sB[buf][0] + (cb - ACH) * 16);
            }
        }
    };

    for (int rep = 0; rep < REP_PROJ; ++rep) {
        f32x4 acc[MI][4] = {};
        stage(0, 0);
        stage(1, BK);
        int cur = 0;
        for (int kt = 0; kt < K; kt += BK) {
            if (kt + BK < K) {
                asm volatile("s_waitcnt vmcnt(6)" ::: "memory");
            } else {
                asm volatile("s_waitcnt vmcnt(0)" ::: "memory");
            }
            __builtin_amdgcn_s_barrier();
            __builtin_amdgcn_sched_barrier(0);
#pragma unroll
            for (int ks = 0; ks < 2; ++ks) {
                bf16x8 af[MI], bfr[4];
#pragma unroll
                for (int mi = 0; mi < MI; ++mi) {
                    const int row = wm * (TM / 2) + mi * 16 + lr;
                    af[mi] = *(const bf16x8*)
                        &sA[cur][row * BK + ((ks * 4 + quad) ^ (row & 7)) * 8];
                }
#pragma unroll
                for (int ni = 0; ni < 4; ++ni) {
                    const int row = wn * 64 + ni * 16 + lr;
                    bfr[ni] = *(const bf16x8*)
                        &sB[cur][row * BK + ((ks * 4 + quad) ^ (row & 7)) * 8];
                }
                __builtin_amdgcn_s_setprio(1);
#pragma unroll
                for (int mi = 0; mi < MI; ++mi)
#pragma unroll
                    for (int ni = 0; ni < 4; ++ni)
                        acc[mi][ni] = __builtin_amdgcn_mfma_f32_16x16x32_bf16(
                            af[mi], bfr[ni], acc[mi][ni], 0, 0, 0);
                __builtin_amdgcn_s_setprio(0);
            }
            __builtin_amdgcn_s_barrier();
            __builtin_amdgcn_sched_barrier(0);
            if (kt + 2 * BK < K) stage(cur, kt + 2 * BK);
            cur ^= 1;
        }

#pragma unroll
        for (int mi = 0; mi < MI; ++mi)
#pragma unroll
            for (int ni = 0; ni < 4; ++ni) {
                const int row = m0 + wm * (TM / 2) + mi * 16 + quad * 4;
                const int col = n0 + wn * 64 + ni * 16 + lr;
                const f32x4 vv = acc[mi][ni];
#pragma unroll
                for (int r = 0; r < 4; ++r)
                    C[(size_t)(row + r) * N + col] = (bf16)(vv[r] + bia[ni]);
            }
        // rep boundary safe: last K-iter's closing barrier precedes any LDS
        // overwrite; epilogue is register-only; acc re-zeroed next rep.
    }
}

// ---------------------------------------------------------------------------
__global__ __launch_bounds__(256) void gemm_final_kernel(
    const bf16* __restrict__ A, const bf16* __restrict__ BT,
    const float* __restrict__ bias, float* __restrict__ C) {
    constexpr int K = 1024, N = 1024, BK = 64, TM = 32, MI = 2;
    constexpr int ACH = TM * (BK / 8);        // 256 chunks
    constexpr int TCH = ACH + 128 * (BK / 8); // 1280 chunks -> 5 per thread

    const int orig = blockIdx.x;
    const int flat = (orig & 7) * 64 + (orig >> 3);
    const int m0 = (flat >> 3) * TM, n0 = (flat & 7) * 128;

    __shared__ bf16 sA[2][TM * BK];
    __shared__ bf16 sB[2][128 * BK];
    const int tid = threadIdx.x;
    const int w = tid >> 6, lane = tid & 63;
    const int lr = lane & 15, quad = lane >> 4;

    float bia[2];
#pragma unroll
    for (int ni = 0; ni < 2; ++ni) bia[ni] = bias[n0 + w * 32 + ni * 16 + lr];

    auto stage = [&](int buf, int kt) {
#pragma unroll
        for (int kk = 0; kk < TCH / 256; ++kk) {
            const int cb = kk * 256 + w * 64;
            const int p = cb + lane;
            if (cb < ACH) {
                const int row = p >> 3, chl = p & 7;
                const int chg = chl ^ (row & 7);
                async_load16(A + (size_t)(m0 + row) * K + kt + chg * 8,
                             (char*)&sA[buf][0] + cb * 16);
            } else {
                const int p2 = p - ACH, row = p2 >> 3, chl = p2 & 7;
                const int chg = chl ^ (row & 7);
                async_load16(BT + (size_t)(n0 + row) * K + kt + chg * 8,
                             (char*)&sB[buf][0] + (cb - ACH) * 16);
            }
        }
    };

    for (int rep = 0; rep < REP_FINAL; ++rep) {
        f32x4 acc[MI][2] = {};
        stage(0, 0);
        stage(1, BK);
        int cur = 0;
        for (int kt = 0; kt < K; kt += BK) {
            if (kt + BK < K) {
                asm volatile("s_waitcnt vmcnt(5)" ::: "memory");
            } else {
                asm volatile("s_waitcnt vmcnt(0)" ::: "memory");
            }
            __builtin_amdgcn_s_barrier();
            __builtin_amdgcn_sched_barrier(0);
#pragma unroll
            for (int ks = 0; ks < 2; ++ks) {
                bf16x8 af[MI], bfr[2];
#pragma unroll
                for (int mi = 0; mi < MI; ++mi) {
                    const int row = mi * 16 + lr;
                    af[mi] = *(const bf16x8*)
                        &sA[cur][row * BK + ((ks * 4 + quad) ^ (row & 7)) * 8];
                }
#pragma unroll
                for (int ni = 0; ni < 2; ++ni) {
                    const int row = w * 32 + ni * 16 + lr;
                    bfr[ni] = *(const bf16x8*)
                        &sB[cur][row * BK + ((ks * 4 + quad) ^ (row & 7)) * 8];
                }
                __builtin_amdgcn_s_setprio(1);
#pragma unroll
                for (int mi = 0; mi < MI; ++mi)
#pragma unroll
                    for (int ni = 0; ni < 2; ++ni)
                        acc[mi][ni] = __builtin_amdgcn_mfma_f32_16x16x32_bf16(
                            af[mi], bfr[ni], acc[mi][ni], 0, 0, 0);
                __builtin_amdgcn_s_setprio(0);
            }
            __builtin_amdgcn_s_barrier();
            __builtin_amdgcn_sched_barrier(0);
            if (kt + 2 * BK < K) stage(cur, kt + 2 * BK);
            cur ^= 1;
        }

#pragma unroll
        for (int mi = 0; mi < MI; ++mi)
#pragma unroll
            for (int ni = 0; ni < 2; ++ni) {
                const int row = m0 + mi * 16 + quad * 4;
                const int col = n0 + w * 32 + ni * 16 + lr;
                const f32x4 vv = acc[mi][ni];
#pragma unroll
                for (int r = 0; r < 4; ++r)
                    C[(size_t)(row + r) * N + col] = vv[r] + bia[ni];
            }
    }
}

// ---------------------------------------------------------------------------
__global__ __launch_bounds__(256) void attn_kernel(
    const bf16* __restrict__ qp, const bf16* __restrict__ kp, const bf16* __restrict__ vp,
    bf16* __restrict__ ao) {
    const int wv = threadIdx.x >> 6, lane = threadIdx.x & 63;
    constexpr int NB = NHEAD * SEQ / 4;           // 8192 blocks
    const int bid = (blockIdx.x & 7) * (NB >> 3) + (blockIdx.x >> 3);
    const int p = bid * 4 + wv;
    const int s = __builtin_amdgcn_readfirstlane(p & (SEQ - 1));
    const int h = __builtin_amdgcn_readfirstlane(p >> 11);
    const int hbase = h * DHEAD;
    const int hoff = hbase + lane;

    const int tt = (s >> 8) & 7, hh = (s >> 4) & 15;
    const int win = (s < 3) ? s : 3;
    const int cnt = tt + hh + win + 1;

    for (int rep = 0; rep < REP_ATTN; ++rep) {
        int t[NZPAD];
#pragma unroll
        for (int c = 0; c < NZPAD; ++c) t[c] = support_idx(s, c, tt, hh, cnt);

        const int c_lane = lane & 31;
        const int fo = (lane >> 5) << 5;
        const int myT = support_idx(s, c_lane, tt, hh, cnt);

        const bf16x8* qrow = (const bf16x8*)(qp + (size_t)s * DMODEL + hbase + fo);
        const bf16x8* krow = (const bf16x8*)(kp + (size_t)myT * DMODEL + hbase + fo);
        bf16x8 qc[4], kc[4];
#pragma unroll
        for (int j = 0; j < 4; ++j) { qc[j] = qrow[j]; kc[j] = krow[j]; }

        float vvv[NZPAD];
#pragma unroll
        for (int c = 0; c < NZPAD; ++c)
            vvv[c] = (float)vp[(size_t)t[c] * DMODEL + hoff];

        float dot = 0.f;
        __builtin_amdgcn_s_setprio(1);
#pragma unroll
        for (int j = 0; j < 4; ++j)
#pragma unroll
            for (int e = 0; e < 8; ++e)
                dot = fmaf((float)qc[j][e], (float)kc[j][e], dot);
        __builtin_amdgcn_s_setprio(0);
        dot += __shfl_xor(dot, 32);

        const float logit = (c_lane < cnt) ? dot * 0.125f : -1e30f;
        float m = logit;
        m = fmaxf(m, __shfl_xor(m, 1)); m = fmaxf(m, __shfl_xor(m, 2));
        m = fmaxf(m, __shfl_xor(m, 4)); m = fmaxf(m, __shfl_xor(m, 8));
        m = fmaxf(m, __shfl_xor(m, 16));
        const float e = __expf(logit - m);
        float ssum = e;
        ssum += __shfl_xor(ssum, 1); ssum += __shfl_xor(ssum, 2);
        ssum += __shfl_xor(ssum, 4); ssum += __shfl_xor(ssum, 8);
        ssum += __shfl_xor(ssum, 16);
        const float prob = e / ssum;

        float acc = 0.f;
        __builtin_amdgcn_s_setprio(1);
#pragma unroll
        for (int c = 0; c < NZPAD; ++c) {
            const float pc = __uint_as_float(
                __builtin_amdgcn_readlane(__float_as_uint(prob), c));
            acc = fmaf(pc, vvv[c], acc);
        }
        __builtin_amdgcn_s_setprio(0);
        ao[(size_t)s * DMODEL + hoff] = (bf16)acc;
    }
}

// ---------------------------------------------------------------------------
extern "C" void kernel_launch(void* const* d_in, const int* in_sizes, int n_in,
                              void* d_out, int out_size, void* d_ws, size_t ws_size,
                              hipStream_t stream) {
    const float* query = (const float*)d_in[0];
    const float* key   = (const float*)d_in[1];
    const float* value = (const float*)d_in[2];
    const float* wq = (const float*)d_in[3];
    const float* bq = (const float*)d_in[4];
    const float* wk = (const float*)d_in[5];
    const float* bk = (const float*)d_in[6];
    const float* wv = (const float*)d_in[7];
    const float* bv = (const float*)d_in[8];
    const float* wo = (const float*)d_in[9];
    const float* bo = (const float*)d_in[10];
    float* out = (float*)d_out;

    char* ws = (char*)d_ws;
    auto alloc = [&](size_t bytes) {
        char* p = ws;
        ws += (bytes + 255) & ~(size_t)255;
        return p;
    };
    bf16* qx  = (bf16*)alloc((size_t)SEQ * DMODEL * 2);
    bf16* kx  = (bf16*)alloc((size_t)SEQ * DMODEL * 2);
    bf16* vx  = (bf16*)alloc((size_t)SEQ * DMODEL * 2);
    bf16* wqT = (bf16*)alloc((size_t)DMODEL * DMODEL * 2);
    bf16* wkT = (bf16*)alloc((size_t)DMODEL * DMODEL * 2);
    bf16* wvT = (bf16*)alloc((size_t)DMODEL * DMODEL * 2);
    bf16* woT = (bf16*)alloc((size_t)DMODEL * DMODEL * 2);
    bf16* qp  = (bf16*)alloc((size_t)SEQ * DMODEL * 2);
    bf16* kp  = (bf16*)alloc((size_t)SEQ * DMODEL * 2);
    bf16* vp  = (bf16*)alloc((size_t)SEQ * DMODEL * 2);
    bf16* ao  = (bf16*)alloc((size_t)SEQ * DMODEL * 2);

    // MEASUREMENT ROUND: internal rep loops make every dispatch > fill
    // duration so rocprof top-5 shows per-kernel durations + counters.
    prep_kernel<<<dim3(CAST_BLOCKS + TR_BLOCKS), 256, 0, stream>>>(
        query, key, value, qx, kx, vx,
        wq, wk, wv, wo, wqT, wkT, wvT, woT);
    proj3_kernel<<<dim3(768), 256, 0, stream>>>(
        qx, kx, vx, wqT, wkT, wvT, bq, bk, bv, qp, kp, vp);
    attn_kernel<<<dim3(NHEAD * SEQ / 4), 256, 0, stream>>>(qp, kp, vp, ao);
    gemm_final_kernel<<<dim3(512), 256, 0, stream>>>(ao, woT, bo, out);
}

// Round 12
// 161.263 us; speedup vs baseline: 1.2894x; 1.2894x over previous
//
#include <hip/hip_runtime.h>
#include <hip/hip_bf16.h>
#include <cstdint>
#include <math.h>

// Problem constants
#define SEQ    2048
#define DMODEL 1024
#define NHEAD  16
#define DHEAD  64
#define NZPAD  32   // per-row nonzero count padded to 32 (analytic max = 26)

typedef __bf16 bf16;
typedef __bf16 bf16x4 __attribute__((ext_vector_type(4)));
typedef __bf16 bf16x8 __attribute__((ext_vector_type(8)));
typedef float  f32x4  __attribute__((ext_vector_type(4)));

typedef __attribute__((address_space(3))) uint32_t lds_u32;
typedef __attribute__((address_space(1))) const uint32_t global_u32;

__device__ __forceinline__ void async_load16(const void* g, void* l) {
    __builtin_amdgcn_global_load_lds((global_u32*)g, (lds_u32*)l, 16, 0, 0);
}

// Analytic sparse-layout support for ORIGIN_SHAPE=(8,16,16), LOCAL_BLOCKS=3:
// support(s) = {t'*256 + (s&255), t'<t} u {(s&0x700) + h'*16 + (s&15), h'<h}
//            u {s-win..s}, win = min(s,3); disjoint; cnt = t+h+win+1 <= 26.
__device__ __forceinline__ int support_idx(int s, int c, int tt, int hh,
                                           int cnt) {
    const int jA = c * 256 + (s & 255);                    // axial-T, c < tt
    const int jB = (s & 0x700) + (c - tt) * 16 + (s & 15); // axial-H
    const int jC = s - (cnt - 1 - c);                      // causal window
    return c < tt ? jA : (c < tt + hh ? jB : (c < cnt ? jC : s));
}

// ---------------------------------------------------------------------------
// Merged preprocessing.
//  - cast section: 1536 blocks, 16 elems/thread (4x float4 -> 2x bf16x8).
//  - TR section: 1024 blocks, 64x64 float4 tiles.
// SESSION LEDGER (rounds 0-11): kernels sum to ~25-30us (rep-delta
// measurement, round 11); ~130us of the total is fixed harness poison-fill
// overhead (256MiB fills at 80% HBM write BW), invariant to dispatch count
// (round 6) and kernel content. Locality wins: XCD-chunked GEMM grids +
// attn swizzle (-14us). Nulls: counted-vmcnt x3, prep vectorization. Loss:
// cooperative mega-fusion (occupancy collapse, -170us).
#define CAST_BLOCKS 1536
#define TR_BLOCKS   1024

__global__ __launch_bounds__(256) void prep_kernel(
    const float* __restrict__ q, const float* __restrict__ k, const float* __restrict__ v,
    bf16* __restrict__ qx, bf16* __restrict__ kx, bf16* __restrict__ vx,
    const float* __restrict__ w0, const float* __restrict__ w1,
    const float* __restrict__ w2, const float* __restrict__ w3,
    bf16* __restrict__ t0, bf16* __restrict__ t1,
    bf16* __restrict__ t2, bf16* __restrict__ t3) {
    __shared__ float tile[64][65];
    const int bid = blockIdx.x;
    if (bid < CAST_BLOCKS) {
        // ---- fp32 -> bf16 cast of q/k/v (16 elems per thread)
        const int z = bid >> 9;                   // 512 blocks per tensor
        const float* src = (z == 0) ? q : (z == 1) ? k : v;
        bf16* dst        = (z == 0) ? qx : (z == 1) ? kx : vx;
        const int i = (bid & 511) * 256 + threadIdx.x;
        const float4* s4 = (const float4*)src;
        float4 a0 = s4[i * 4 + 0];
        float4 a1 = s4[i * 4 + 1];
        float4 a2 = s4[i * 4 + 2];
        float4 a3 = s4[i * 4 + 3];
        bf16x8 o0, o1;
        o0[0] = (bf16)a0.x; o0[1] = (bf16)a0.y; o0[2] = (bf16)a0.z; o0[3] = (bf16)a0.w;
        o0[4] = (bf16)a1.x; o0[5] = (bf16)a1.y; o0[6] = (bf16)a1.z; o0[7] = (bf16)a1.w;
        o1[0] = (bf16)a2.x; o1[1] = (bf16)a2.y; o1[2] = (bf16)a2.z; o1[3] = (bf16)a2.w;
        o1[4] = (bf16)a3.x; o1[5] = (bf16)a3.y; o1[6] = (bf16)a3.z; o1[7] = (bf16)a3.w;
        ((bf16x8*)dst)[i * 2 + 0] = o0;
        ((bf16x8*)dst)[i * 2 + 1] = o1;
    } else {
        // ---- W[K][N] fp32 -> WT[N][K] bf16, 64x64 tile, float4 I/O
        const int b = bid - CAST_BLOCKS;
        const int z = b >> 8, rem = b & 255;
        const float* w = (z == 0) ? w0 : (z == 1) ? w1 : (z == 2) ? w2 : w3;
        bf16* t        = (z == 0) ? t0 : (z == 1) ? t1 : (z == 2) ? t2 : t3;
        const int kb = (rem >> 4) * 64, nb = (rem & 15) * 64;
        const int c4 = threadIdx.x & 15, rg = threadIdx.x >> 4;
#pragma unroll
        for (int i = 0; i < 4; ++i) {
            const int row = rg * 4 + i;
            const float4 vv = *(const float4*)&w[(size_t)(kb + row) * DMODEL + nb + c4 * 4];
            tile[row][c4 * 4 + 0] = vv.x; tile[row][c4 * 4 + 1] = vv.y;
            tile[row][c4 * 4 + 2] = vv.z; tile[row][c4 * 4 + 3] = vv.w;
        }
        __syncthreads();
#pragma unroll
        for (int i = 0; i < 4; ++i) {
            const int n = rg * 4 + i;
            bf16x4 o;
            o[0] = (bf16)tile[c4 * 4 + 0][n]; o[1] = (bf16)tile[c4 * 4 + 1][n];
            o[2] = (bf16)tile[c4 * 4 + 2][n]; o[3] = (bf16)tile[c4 * 4 + 3][n];
            *(bf16x4*)&t[(size_t)(nb + n) * DMODEL + kb + c4 * 4] = o;
        }
    }
}

// ---------------------------------------------------------------------------
// proj3: TM=64, BK=64, 2-deep counted vmcnt(6) pipeline, XOR-swizzled LDS
// (rule #21: inverse-swizzled global source + same XOR on ds_read). 1-D
// grid, XCD-chunked decode: each XCD owns a contiguous run of 96 blocks ->
// working set (12 A-tiles 1.5MB + one BT panel 2MB) fits the private 4MB L2.
__global__ __launch_bounds__(256) void proj3_kernel(
    const bf16* __restrict__ qx, const bf16* __restrict__ kx, const bf16* __restrict__ vx,
    const bf16* __restrict__ wqT, const bf16* __restrict__ wkT, const bf16* __restrict__ wvT,
    const float* __restrict__ bq, const float* __restrict__ bk, const float* __restrict__ bv,
    bf16* __restrict__ qp, bf16* __restrict__ kp, bf16* __restrict__ vp) {
    constexpr int K = 1024, N = 1024, BK = 64, TM = 64, MI = 2;
    constexpr int ACH = TM * (BK / 8);        // 512 chunks
    constexpr int TCH = ACH + 128 * (BK / 8); // 1536 chunks -> 6 per thread

    // XCD-chunked decode (768 blocks, 96 per XCD, bijective: 768 % 8 == 0)
    const int orig = blockIdx.x;
    const int flat = (orig & 7) * 96 + (orig >> 3);
    const int z = flat >> 8;                  // 256 blocks per z
    const int rem = flat & 255;
    const int m0 = (rem >> 3) * TM, n0 = (rem & 7) * 128;

    const bf16* A   = (z == 0) ? qx : (z == 1) ? kx : vx;
    const bf16* BT  = (z == 0) ? wqT : (z == 1) ? wkT : wvT;
    const float* bi = (z == 0) ? bq : (z == 1) ? bk : bv;
    bf16* C         = (z == 0) ? qp : (z == 1) ? kp : vp;

    __shared__ bf16 sA[2][TM * BK];
    __shared__ bf16 sB[2][128 * BK];
    const int tid = threadIdx.x;
    const int w = tid >> 6, lane = tid & 63;
    const int wm = w >> 1, wn = w & 1;
    const int lr = lane & 15, quad = lane >> 4;

    f32x4 acc[MI][4] = {};
    float bia[4];
#pragma unroll
    for (int ni = 0; ni < 4; ++ni) bia[ni] = bi[n0 + wn * 64 + ni * 16 + lr];

    auto stage = [&](int buf, int kt) {
#pragma unroll
        for (int kk = 0; kk < TCH / 256; ++kk) {
            const int cb = kk * 256 + w * 64;     // wave-uniform chunk base
            const int p  = cb + lane;             // linear LDS slot
            if (cb < ACH) {
                const int row = p >> 3, chl = p & 7;
                const int chg = chl ^ (row & 7);  // inverse-swizzled source
                async_load16(A + (size_t)(m0 + row) * K + kt + chg * 8,
                             (char*)&sA[buf][0] + cb * 16);
            } else {
                const int p2 = p - ACH, row = p2 >> 3, chl = p2 & 7;
                const int chg = chl ^ (row & 7);
                async_load16(BT + (size_t)(n0 + row) * K + kt + chg * 8,
                             (char*)&sB[buf][0] + (cb - ACH) * 16);
            }
        }
    };

    stage(0, 0);
    stage(1, BK);
    int cur = 0;
    for (int kt = 0; kt < K; kt += BK) {
        if (kt + BK < K) {
            asm volatile("s_waitcnt vmcnt(6)" ::: "memory");  // cur tile landed
        } else {
            asm volatile("s_waitcnt vmcnt(0)" ::: "memory");  // epilogue drain
        }
        __builtin_amdgcn_s_barrier();
        __builtin_amdgcn_sched_barrier(0);
#pragma unroll
        for (int ks = 0; ks < 2; ++ks) {            // two 16x16x32 k-substeps
            bf16x8 af[MI], bfr[4];
#pragma unroll
            for (int mi = 0; mi < MI; ++mi) {
                const int row = wm * (TM / 2) + mi * 16 + lr;
                af[mi] = *(const bf16x8*)
                    &sA[cur][row * BK + ((ks * 4 + quad) ^ (row & 7)) * 8];
            }
#pragma unroll
            for (int ni = 0; ni < 4; ++ni) {
                const int row = wn * 64 + ni * 16 + lr;
                bfr[ni] = *(const bf16x8*)
                    &sB[cur][row * BK + ((ks * 4 + quad) ^ (row & 7)) * 8];
            }
            __builtin_amdgcn_s_setprio(1);
#pragma unroll
            for (int mi = 0; mi < MI; ++mi)
#pragma unroll
                for (int ni = 0; ni < 4; ++ni)
                    acc[mi][ni] = __builtin_amdgcn_mfma_f32_16x16x32_bf16(
                        af[mi], bfr[ni], acc[mi][ni], 0, 0, 0);
            __builtin_amdgcn_s_setprio(0);
        }
        __builtin_amdgcn_s_barrier();               // all waves done reading cur
        __builtin_amdgcn_sched_barrier(0);
        if (kt + 2 * BK < K) stage(cur, kt + 2 * BK);  // restage freed buffer
        cur ^= 1;
    }

#pragma unroll
    for (int mi = 0; mi < MI; ++mi)
#pragma unroll
        for (int ni = 0; ni < 4; ++ni) {
            const int row = m0 + wm * (TM / 2) + mi * 16 + quad * 4;
            const int col = n0 + wn * 64 + ni * 16 + lr;
            const f32x4 vv = acc[mi][ni];
#pragma unroll
            for (int r = 0; r < 4; ++r)
                C[(size_t)(row + r) * N + col] = (bf16)(vv[r] + bia[ni]);
        }
}

// ---------------------------------------------------------------------------
// Final GEMM: C_f32 = A_bf16 @ BT^T + bias. TM=32 (512 blocks = 2/CU) with
// 1x4 wave grid (wave-tile 32x32: 4 ds_read_b128 per substep). 2-deep
// counted pipeline (5 loads/stage -> vmcnt(5)). XCD-chunked decode.
__global__ __launch_bounds__(256) void gemm_final_kernel(
    const bf16* __restrict__ A, const bf16* __restrict__ BT,
    const float* __restrict__ bias, float* __restrict__ C) {
    constexpr int K = 1024, N = 1024, BK = 64, TM = 32, MI = 2;
    constexpr int ACH = TM * (BK / 8);        // 256 chunks
    constexpr int TCH = ACH + 128 * (BK / 8); // 1280 chunks -> 5 per thread

    const int orig = blockIdx.x;              // 512 blocks, 64 per XCD
    const int flat = (orig & 7) * 64 + (orig >> 3);
    const int m0 = (flat >> 3) * TM, n0 = (flat & 7) * 128;

    __shared__ bf16 sA[2][TM * BK];
    __shared__ bf16 sB[2][128 * BK];
    const int tid = threadIdx.x;
    const int w = tid >> 6, lane = tid & 63;  // wn = w (1x4 wave grid)
    const int lr = lane & 15, quad = lane >> 4;

    f32x4 acc[MI][2] = {};
    float bia[2];
#pragma unroll
    for (int ni = 0; ni < 2; ++ni) bia[ni] = bias[n0 + w * 32 + ni * 16 + lr];

    auto stage = [&](int buf, int kt) {
#pragma unroll
        for (int kk = 0; kk < TCH / 256; ++kk) {
            const int cb = kk * 256 + w * 64;
            const int p = cb + lane;
            if (cb < ACH) {
                const int row = p >> 3, chl = p & 7;
                const int chg = chl ^ (row & 7);
                async_load16(A + (size_t)(m0 + row) * K + kt + chg * 8,
                             (char*)&sA[buf][0] + cb * 16);
            } else {
                const int p2 = p - ACH, row = p2 >> 3, chl = p2 & 7;
                const int chg = chl ^ (row & 7);
                async_load16(BT + (size_t)(n0 + row) * K + kt + chg * 8,
                             (char*)&sB[buf][0] + (cb - ACH) * 16);
            }
        }
    };

    stage(0, 0);
    stage(1, BK);
    int cur = 0;
    for (int kt = 0; kt < K; kt += BK) {
        if (kt + BK < K) {
            asm volatile("s_waitcnt vmcnt(5)" ::: "memory");
        } else {
            asm volatile("s_waitcnt vmcnt(0)" ::: "memory");
        }
        __builtin_amdgcn_s_barrier();
        __builtin_amdgcn_sched_barrier(0);
#pragma unroll
        for (int ks = 0; ks < 2; ++ks) {
            bf16x8 af[MI], bfr[2];
#pragma unroll
            for (int mi = 0; mi < MI; ++mi) {
                const int row = mi * 16 + lr;
                af[mi] = *(const bf16x8*)
                    &sA[cur][row * BK + ((ks * 4 + quad) ^ (row & 7)) * 8];
            }
#pragma unroll
            for (int ni = 0; ni < 2; ++ni) {
                const int row = w * 32 + ni * 16 + lr;
                bfr[ni] = *(const bf16x8*)
                    &sB[cur][row * BK + ((ks * 4 + quad) ^ (row & 7)) * 8];
            }
            __builtin_amdgcn_s_setprio(1);
#pragma unroll
            for (int mi = 0; mi < MI; ++mi)
#pragma unroll
                for (int ni = 0; ni < 2; ++ni)
                    acc[mi][ni] = __builtin_amdgcn_mfma_f32_16x16x32_bf16(
                        af[mi], bfr[ni], acc[mi][ni], 0, 0, 0);
            __builtin_amdgcn_s_setprio(0);
        }
        __builtin_amdgcn_s_barrier();
        __builtin_amdgcn_sched_barrier(0);
        if (kt + 2 * BK < K) stage(cur, kt + 2 * BK);
        cur ^= 1;
    }

#pragma unroll
    for (int mi = 0; mi < MI; ++mi)
#pragma unroll
        for (int ni = 0; ni < 2; ++ni) {
            const int row = m0 + mi * 16 + quad * 4;
            const int col = n0 + w * 32 + ni * 16 + lr;
            const f32x4 vv = acc[mi][ni];
#pragma unroll
            for (int r = 0; r < 4; ++r)
                C[(size_t)(row + r) * N + col] = vv[r] + bia[ni];
        }
}

// ---------------------------------------------------------------------------
// Sparse attention: analytic support in-register (no nzidx memory),
// lane=candidate QK layout, XCD-chunked block swizzle (2 heads = 1.5MB per
// XCD fits private L2), setprio around the FMA clusters.
__global__ __launch_bounds__(256) void attn_kernel(
    const bf16* __restrict__ qp, const bf16* __restrict__ kp, const bf16* __restrict__ vp,
    bf16* __restrict__ ao) {
    const int wv = threadIdx.x >> 6, lane = threadIdx.x & 63;
    constexpr int NB = NHEAD * SEQ / 4;           // 8192 blocks
    const int bid = (blockIdx.x & 7) * (NB >> 3) + (blockIdx.x >> 3);
    const int p = bid * 4 + wv;
    const int s = __builtin_amdgcn_readfirstlane(p & (SEQ - 1));
    const int h = __builtin_amdgcn_readfirstlane(p >> 11);
    const int hbase = h * DHEAD;
    const int hoff = hbase + lane;

    const int tt = (s >> 8) & 7, hh = (s >> 4) & 15;
    const int win = (s < 3) ? s : 3;
    const int cnt = tt + hh + win + 1;

    int t[NZPAD];                                  // s-uniform -> scalar regs
#pragma unroll
    for (int c = 0; c < NZPAD; ++c) t[c] = support_idx(s, c, tt, hh, cnt);

    // --- QK^T, lane=candidate
    const int c_lane = lane & 31;
    const int fo = (lane >> 5) << 5;               // feature offset: 0 or 32
    const int myT = support_idx(s, c_lane, tt, hh, cnt);  // per-lane (VALU)

    const bf16x8* qrow = (const bf16x8*)(qp + (size_t)s * DMODEL + hbase + fo);
    const bf16x8* krow = (const bf16x8*)(kp + (size_t)myT * DMODEL + hbase + fo);
    bf16x8 qc[4], kc[4];
#pragma unroll
    for (int j = 0; j < 4; ++j) { qc[j] = qrow[j]; kc[j] = krow[j]; }

    // hoist V loads (independent of softmax) to overlap latency; lane=feature
    float vvv[NZPAD];
#pragma unroll
    for (int c = 0; c < NZPAD; ++c)
        vvv[c] = (float)vp[(size_t)t[c] * DMODEL + hoff];

    float dot = 0.f;
    __builtin_amdgcn_s_setprio(1);
#pragma unroll
    for (int j = 0; j < 4; ++j)
#pragma unroll
        for (int e = 0; e < 8; ++e)
            dot = fmaf((float)qc[j][e], (float)kc[j][e], dot);
    __builtin_amdgcn_s_setprio(0);
    dot += __shfl_xor(dot, 32);   // combine feature halves -> full dot in lane c

    const float logit = (c_lane < cnt) ? dot * 0.125f : -1e30f;  // 1/sqrt(64)
    float m = logit;
    m = fmaxf(m, __shfl_xor(m, 1)); m = fmaxf(m, __shfl_xor(m, 2));
    m = fmaxf(m, __shfl_xor(m, 4)); m = fmaxf(m, __shfl_xor(m, 8));
    m = fmaxf(m, __shfl_xor(m, 16));
    const float e = __expf(logit - m);
    float ssum = e;
    ssum += __shfl_xor(ssum, 1); ssum += __shfl_xor(ssum, 2);
    ssum += __shfl_xor(ssum, 4); ssum += __shfl_xor(ssum, 8);
    ssum += __shfl_xor(ssum, 16);
    const float prob = e / ssum;

    float acc = 0.f;
    __builtin_amdgcn_s_setprio(1);
#pragma unroll
    for (int c = 0; c < NZPAD; ++c) {
        const float pc = __uint_as_float(
            __builtin_amdgcn_readlane(__float_as_uint(prob), c));
        acc = fmaf(pc, vvv[c], acc);
    }
    __builtin_amdgcn_s_setprio(0);
    ao[(size_t)s * DMODEL + hoff] = (bf16)acc;
}

// ---------------------------------------------------------------------------
extern "C" void kernel_launch(void* const* d_in, const int* in_sizes, int n_in,
                              void* d_out, int out_size, void* d_ws, size_t ws_size,
                              hipStream_t stream) {
    const float* query = (const float*)d_in[0];
    const float* key   = (const float*)d_in[1];
    const float* value = (const float*)d_in[2];
    const float* wq = (const float*)d_in[3];
    const float* bq = (const float*)d_in[4];
    const float* wk = (const float*)d_in[5];
    const float* bk = (const float*)d_in[6];
    const float* wv = (const float*)d_in[7];
    const float* bv = (const float*)d_in[8];
    const float* wo = (const float*)d_in[9];
    const float* bo = (const float*)d_in[10];
    float* out = (float*)d_out;

    char* ws = (char*)d_ws;
    auto alloc = [&](size_t bytes) {
        char* p = ws;
        ws += (bytes + 255) & ~(size_t)255;
        return p;
    };
    bf16* qx  = (bf16*)alloc((size_t)SEQ * DMODEL * 2);
    bf16* kx  = (bf16*)alloc((size_t)SEQ * DMODEL * 2);
    bf16* vx  = (bf16*)alloc((size_t)SEQ * DMODEL * 2);
    bf16* wqT = (bf16*)alloc((size_t)DMODEL * DMODEL * 2);
    bf16* wkT = (bf16*)alloc((size_t)DMODEL * DMODEL * 2);
    bf16* wvT = (bf16*)alloc((size_t)DMODEL * DMODEL * 2);
    bf16* woT = (bf16*)alloc((size_t)DMODEL * DMODEL * 2);
    bf16* qp  = (bf16*)alloc((size_t)SEQ * DMODEL * 2);
    bf16* kp  = (bf16*)alloc((size_t)SEQ * DMODEL * 2);
    bf16* vp  = (bf16*)alloc((size_t)SEQ * DMODEL * 2);
    bf16* ao  = (bf16*)alloc((size_t)SEQ * DMODEL * 2);

    // 1. merged prep: vectorized casts + 64x64 float4 weight transposes
    prep_kernel<<<dim3(CAST_BLOCKS + TR_BLOCKS), 256, 0, stream>>>(
        query, key, value, qx, kx, vx,
        wq, wk, wv, wo, wqT, wkT, wvT, woT);
    // 2. q/k/v projections (768 blocks, XCD-chunked 1-D grid)
    proj3_kernel<<<dim3(768), 256, 0, stream>>>(
        qx, kx, vx, wqT, wkT, wvT, bq, bk, bv, qp, kp, vp);
    // 3. sparse attention (analytic support, XCD-chunked swizzle)
    attn_kernel<<<dim3(NHEAD * SEQ / 4), 256, 0, stream>>>(qp, kp, vp, ao);
    // 4. output projection to fp32 (512 blocks, XCD-chunked 1-D grid)
    gemm_final_kernel<<<dim3(512), 256, 0, stream>>>(ao, woT, bo, out);
}